// Round 6
// baseline (845.238 us; speedup 1.0000x reference)
//
#include <hip/hip_runtime.h>
#include <hip/hip_fp16.h>
#include <math.h>

// Shapes (fixed): B=4, C=512, H=W=64 -> HW=4096
constexpr int BATCH = 4;
constexpr int HWDIM = 4096;
constexpr long CNT  = 2097152;               // 4096*512 elems per batch
constexpr int GSIZE = 65536;
constexpr float GN_EPS = 1e-5f;

typedef __attribute__((ext_vector_type(8))) _Float16 f16x8;
typedef __attribute__((ext_vector_type(4))) float f32x4;

__device__ __forceinline__ unsigned pkf16(float a, float b) {
  __half ha = __float2half(a), hb = __float2half(b);   // RTN
  return (unsigned)__half_as_ushort(ha) | ((unsigned)__half_as_ushort(hb) << 16);
}
__device__ __forceinline__ float2 up2(unsigned u) {
  __half2 h = *(__half2*)&u;
  return __half22float2(h);
}

// ---------------- GroupNorm ----------------
__global__ void gn_stats_kernel(const float* __restrict__ x,
                                float* __restrict__ mu, float* __restrict__ rs) {
  const int grp = blockIdx.x;
  const float4* p = (const float4*)(x + (long)grp * GSIZE);
  float s = 0.f, q = 0.f;
  for (int i = threadIdx.x; i < GSIZE / 4; i += 256) {
    float4 v = p[i];
    s += (v.x + v.y) + (v.z + v.w);
    q += (v.x * v.x + v.y * v.y) + (v.z * v.z + v.w * v.w);
  }
  #pragma unroll
  for (int o = 32; o > 0; o >>= 1) { s += __shfl_xor(s, o, 64); q += __shfl_xor(q, o, 64); }
  __shared__ float ls[4], lq[4];
  if ((threadIdx.x & 63) == 0) { ls[threadIdx.x >> 6] = s; lq[threadIdx.x >> 6] = q; }
  __syncthreads();
  if (threadIdx.x == 0) {
    float S = (ls[0] + ls[1]) + (ls[2] + ls[3]);
    float Q = (lq[0] + lq[1]) + (lq[2] + lq[3]);
    float m = S * (1.f / GSIZE);
    float var = Q * (1.f / GSIZE) - m * m;
    mu[grp] = m; rs[grp] = rsqrtf(var + GN_EPS);
  }
}

__global__ void gn_norm_f16(const float* __restrict__ x,
                            const float* __restrict__ mu, const float* __restrict__ rs,
                            const float* __restrict__ gw, const float* __restrict__ gb,
                            unsigned short* __restrict__ h) {
  long i = ((long)blockIdx.x * 256 + threadIdx.x) * 4;
  int c   = (int)((i >> 12) & 511);
  int grp = (int)(i >> 16);
  float m = mu[grp], r = rs[grp];
  float w = gw[c] * r;
  float bia = gb[c] - m * w;
  float4 v = *(const float4*)(x + i);
  *(uint2*)(h + i) = (uint2){ pkf16(v.x * w + bia, v.y * w + bia),
                              pkf16(v.z * w + bia, v.w * w + bia) };
}

// ---------------- weights -> fp16 ----------------
__global__ void wcvt(const float* __restrict__ w0, const float* __restrict__ w1,
                     const float* __restrict__ w2, const float* __restrict__ w3,
                     unsigned short* __restrict__ o) {
  const float* src = blockIdx.y == 0 ? w0 : blockIdx.y == 1 ? w1 : blockIdx.y == 2 ? w2 : w3;
  long e = ((long)blockIdx.x * 256 + threadIdx.x) * 4;
  float4 v = *(const float4*)(src + e);
  *(uint2*)(o + (long)blockIdx.y * 262144 + e) = (uint2){ pkf16(v.x, v.y), pkf16(v.z, v.w) };
}

// ---------------- Unified direct-register fp16 MFMA GEMM ----------------
// C[m,n] = sum_k A[m*lda+k] * B[n*ldb+k] (+bias[n]) ; 128x128 tile, 4 waves 2x2.
// NO LDS staging, NO barriers in the K-loop: each wave loads its own fragments
// global->VGPR (dwordx4 = 16 rows x 64B full lines) with a one-step ping-pong
// prefetch; the compiler emits fine-grained vmcnt waits (the pattern the
// 2-barrier DMA structure could not express). K multiple of 64.
// z-dim: A += z*zK, B += z*zK (split-K), out += z*zO (partial planes).
// OMODE 1: fp16 out via LDS-transposed coalesced epilogue (stride 136: 2-way max).
// OMODE 0: f32 out + bias + res (final out-projection).
template<int OMODE, bool HASBIAS, bool SWZ>
__launch_bounds__(256, 3)
__global__ void mm_f16(const unsigned short* __restrict__ A,
                       const unsigned short* __restrict__ B,
                       const float* __restrict__ bias, const float* __restrict__ res,
                       void* __restrict__ outv,
                       int lda, int ldb, int ldc, int K, long zK, long zO) {
  __shared__ __align__(16) unsigned short LB[OMODE == 1 ? 17408 : 16];
  int bx = blockIdx.x, by = blockIdx.y;
  if (SWZ) {                       // 4x4 block patches for XCD-L2 locality (grid 32x32)
    int id = by * 32 + bx;
    int sid = id >> 4, wi = id & 15;
    bx = (sid & 7) * 4 + (wi & 3);
    by = (sid >> 3) * 4 + (wi >> 2);
  }
  const int m0 = bx * 128, n0 = by * 128;
  A += (long)blockIdx.z * zK;
  B += (long)blockIdx.z * zK;

  const int t = threadIdx.x, lane = t & 63, w = t >> 6, wm = w & 1, wn = w >> 1;
  const int lm = lane & 15, qd = lane >> 4;

  // fragment row base pointers (A[m][k]: m=lane&15, k=quad*8+j)
  const unsigned short* Ap[4];
  const unsigned short* Bp[4];
  #pragma unroll
  for (int i = 0; i < 4; i++) {
    Ap[i] = A + (long)(m0 + wm * 64 + i * 16 + lm) * lda + qd * 8;
    Bp[i] = B + (long)(n0 + wn * 64 + i * 16 + lm) * ldb + qd * 8;
  }

  f32x4 acc[4][4];
  #pragma unroll
  for (int i = 0; i < 4; i++)
    #pragma unroll
    for (int j = 0; j < 4; j++) acc[i][j] = (f32x4){0.f, 0.f, 0.f, 0.f};

  f16x8 a0[4], b0[4], a1[4], b1[4];
  #pragma unroll
  for (int i = 0; i < 4; i++) { a0[i] = *(const f16x8*)(Ap[i]); b0[i] = *(const f16x8*)(Bp[i]); }

  for (int kk = 32; kk < K - 32; kk += 64) {
    #pragma unroll
    for (int i = 0; i < 4; i++) { a1[i] = *(const f16x8*)(Ap[i] + kk); b1[i] = *(const f16x8*)(Bp[i] + kk); }
    #pragma unroll
    for (int i = 0; i < 4; i++)
      #pragma unroll
      for (int j = 0; j < 4; j++)
        acc[i][j] = __builtin_amdgcn_mfma_f32_16x16x32_f16(a0[i], b0[j], acc[i][j], 0, 0, 0);
    #pragma unroll
    for (int i = 0; i < 4; i++) { a0[i] = *(const f16x8*)(Ap[i] + kk + 32); b0[i] = *(const f16x8*)(Bp[i] + kk + 32); }
    #pragma unroll
    for (int i = 0; i < 4; i++)
      #pragma unroll
      for (int j = 0; j < 4; j++)
        acc[i][j] = __builtin_amdgcn_mfma_f32_16x16x32_f16(a1[i], b1[j], acc[i][j], 0, 0, 0);
  }
  #pragma unroll
  for (int i = 0; i < 4; i++) { a1[i] = *(const f16x8*)(Ap[i] + K - 32); b1[i] = *(const f16x8*)(Bp[i] + K - 32); }
  #pragma unroll
  for (int i = 0; i < 4; i++)
    #pragma unroll
    for (int j = 0; j < 4; j++)
      acc[i][j] = __builtin_amdgcn_mfma_f32_16x16x32_f16(a0[i], b0[j], acc[i][j], 0, 0, 0);
  #pragma unroll
  for (int i = 0; i < 4; i++)
    #pragma unroll
    for (int j = 0; j < 4; j++)
      acc[i][j] = __builtin_amdgcn_mfma_f32_16x16x32_f16(a1[i], b1[j], acc[i][j], 0, 0, 0);

  const int quad = qd;
  if (OMODE == 1) {
    unsigned short* outp = (unsigned short*)outv + (long)blockIdx.z * zO;
    #pragma unroll
    for (int i = 0; i < 4; i++)
      #pragma unroll
      for (int j = 0; j < 4; j++) {
        int rr = wm * 64 + i * 16 + quad * 4;
        int cc = wn * 64 + j * 16 + lm;
        float bb = HASBIAS ? bias[n0 + cc] : 0.f;
        #pragma unroll
        for (int r = 0; r < 4; r++)
          LB[(rr + r) * 136 + cc] = __half_as_ushort(__float2half(acc[i][j][r] + bb));
      }
    __syncthreads();
    #pragma unroll
    for (int k = 0; k < 8; k++) {
      int ro = k * 16 + (t >> 4), col = (t & 15) * 8;
      uint4 vv = *(const uint4*)&LB[ro * 136 + col];
      *(uint4*)(outp + (long)(m0 + ro) * ldc + n0 + col) = vv;
    }
  } else {
    #pragma unroll
    for (int i = 0; i < 4; i++)
      #pragma unroll
      for (int j = 0; j < 4; j++) {
        int nn = m0 + wm * 64 + i * 16 + quad * 4;
        int cc = n0 + wn * 64 + j * 16 + lm;
        float bb = HASBIAS ? bias[cc] : 0.f;
        #pragma unroll
        for (int r = 0; r < 4; r++) {
          long idx = (long)(nn + r) * ldc + cc;
          ((float*)outv)[idx] = acc[i][j][r] + bb + res[idx];
        }
      }
  }
}

// ---------------- Transpose fp16: (512,4096)-view -> [4096][512] ----------------
__global__ void transpose_f16(const unsigned short* __restrict__ qb,
                              const unsigned short* __restrict__ kb,
                              unsigned short* __restrict__ tr) {
  __shared__ __align__(16) unsigned short ld[64 * 72];
  const unsigned short* in = blockIdx.z ? kb : qb;
  unsigned short* o = tr + (blockIdx.z ? 2097152 : 0);
  const int n0 = blockIdx.x * 64, c0 = blockIdx.y * 64;
  const int t = threadIdx.x;
  unsigned* ld32 = (unsigned*)ld;
  {
    const int p = t >> 3, cg = t & 7;
    uint4 r0 = *(const uint4*)(in + (long)(c0 + 2 * p) * 4096 + n0 + 8 * cg);
    uint4 r1 = *(const uint4*)(in + (long)(c0 + 2 * p + 1) * 4096 + n0 + 8 * cg);
    unsigned aw[4] = { r0.x, r0.y, r0.z, r0.w };
    unsigned bw[4] = { r1.x, r1.y, r1.z, r1.w };
    #pragma unroll
    for (int i = 0; i < 4; i++) {
      ld32[(8 * cg + 2 * i) * 36 + p]     = (aw[i] & 0xFFFFu) | (bw[i] << 16);
      ld32[(8 * cg + 2 * i + 1) * 36 + p] = (aw[i] >> 16) | (bw[i] & 0xFFFF0000u);
    }
  }
  __syncthreads();
  {
    const int n = t >> 2, cg2 = t & 3;
    uint4 o0 = *(const uint4*)(ld + n * 72 + 16 * cg2);
    uint4 o1 = *(const uint4*)(ld + n * 72 + 16 * cg2 + 8);
    *(uint4*)(o + (long)(n0 + n) * 512 + c0 + 16 * cg2)     = o0;
    *(uint4*)(o + (long)(n0 + n) * 512 + c0 + 16 * cg2 + 8) = o1;
  }
}

// ---------------- Row softmax: fp16 in, fp16 out, in place ----------------
__global__ void softmax_f16ip(unsigned short* __restrict__ attn) {
  unsigned short* p = attn + (long)blockIdx.x * HWDIM;
  const int t = threadIdx.x;
  uint4 u0 = *(const uint4*)(p + t * 16);
  uint4 u1 = *(const uint4*)(p + t * 16 + 8);
  float v[16];
  {
    unsigned uu[8] = { u0.x, u0.y, u0.z, u0.w, u1.x, u1.y, u1.z, u1.w };
    #pragma unroll
    for (int i = 0; i < 8; i++) { float2 f = up2(uu[i]); v[2*i] = f.x; v[2*i+1] = f.y; }
  }
  float mx = -1e30f;
  #pragma unroll
  for (int i = 0; i < 16; i++) mx = fmaxf(mx, v[i]);
  #pragma unroll
  for (int o = 32; o > 0; o >>= 1) mx = fmaxf(mx, __shfl_xor(mx, o, 64));
  __shared__ float rmax[4], rsum[4];
  if ((t & 63) == 0) rmax[t >> 6] = mx;
  __syncthreads();
  mx = fmaxf(fmaxf(rmax[0], rmax[1]), fmaxf(rmax[2], rmax[3]));
  float s = 0.f;
  #pragma unroll
  for (int i = 0; i < 16; i++) { v[i] = __expf(v[i] - mx); s += v[i]; }
  #pragma unroll
  for (int o = 32; o > 0; o >>= 1) s += __shfl_xor(s, o, 64);
  if ((t & 63) == 0) rsum[t >> 6] = s;
  __syncthreads();
  s = (rsum[0] + rsum[1]) + (rsum[2] + rsum[3]);
  float inv = 1.f / s;
  uint4 w0, w1;
  w0.x = pkf16(v[0]*inv,  v[1]*inv);  w0.y = pkf16(v[2]*inv,  v[3]*inv);
  w0.z = pkf16(v[4]*inv,  v[5]*inv);  w0.w = pkf16(v[6]*inv,  v[7]*inv);
  w1.x = pkf16(v[8]*inv,  v[9]*inv);  w1.y = pkf16(v[10]*inv, v[11]*inv);
  w1.z = pkf16(v[12]*inv, v[13]*inv); w1.w = pkf16(v[14]*inv, v[15]*inv);
  *(uint4*)(p + t * 16)     = w0;
  *(uint4*)(p + t * 16 + 8) = w1;
}

// ---------------- sum 4 fp16 partials -> fp16 ot ----------------
__global__ void add4_f16(const unsigned short* __restrict__ p, unsigned short* __restrict__ o) {
  long e = ((long)blockIdx.x * 256 + threadIdx.x) * 4;
  float sx = 0.f, sy = 0.f, sz = 0.f, sw = 0.f;
  #pragma unroll
  for (int z = 0; z < 4; z++) {
    uint2 u = *(const uint2*)(p + (long)z * 2097152 + e);
    float2 f0 = up2(u.x), f1 = up2(u.y);
    sx += f0.x; sy += f0.y; sz += f1.x; sw += f1.y;
  }
  *(uint2*)(o + e) = (uint2){ pkf16(sx, sy), pkf16(sz, sw) };
}

// ---------------- launch ----------------
extern "C" void kernel_launch(void* const* d_in, const int* in_sizes, int n_in,
                              void* d_out, int out_size, void* d_ws, size_t ws_size,
                              hipStream_t stream) {
  (void)in_sizes; (void)n_in; (void)out_size; (void)ws_size;
  const float* x  = (const float*)d_in[0];
  const float* gw = (const float*)d_in[1];
  const float* gb = (const float*)d_in[2];
  const float* wq = (const float*)d_in[3];
  const float* bq = (const float*)d_in[4];
  const float* wk = (const float*)d_in[5];
  const float* bk = (const float*)d_in[6];
  const float* wv = (const float*)d_in[7];
  const float* bv = (const float*)d_in[8];
  const float* wo = (const float*)d_in[9];
  const float* bo = (const float*)d_in[10];
  float* out = (float*)d_out;

  // Workspace (~124 MB, all fp16 except mu/rs):
  //  [attn16 32MB | h 16MB aliases start][qf 16][kf 16][vf 16][tr 8][pvp 16][ot 16][wf 2][mu/rs]
  unsigned short* attn = (unsigned short*)d_ws;
  unsigned short* h    = attn;                 // dead before first qk write
  unsigned short* qf   = attn + 16777216;
  unsigned short* kf   = qf + 8388608;
  unsigned short* vf   = kf + 8388608;
  unsigned short* tr   = vf + 8388608;
  unsigned short* pvp  = tr + 4194304;
  unsigned short* ot   = pvp + 8388608;
  unsigned short* wf   = ot + 8388608;
  float* mu = (float*)(wf + 1048576);
  float* rs = mu + 128;

  gn_stats_kernel<<<dim3(128), dim3(256), 0, stream>>>(x, mu, rs);
  gn_norm_f16<<<dim3(8192), dim3(256), 0, stream>>>(x, mu, rs, gw, gb, h);
  wcvt<<<dim3(256, 4), dim3(256), 0, stream>>>(wq, wk, wv, wo, wf);

  dim3 gproj(128, 4);
  mm_f16<1, true, false><<<gproj, 256, 0, stream>>>(h, wf,          bq, nullptr, qf, 512, 512, 512, 512, 0, 0);
  mm_f16<1, true, false><<<gproj, 256, 0, stream>>>(h, wf + 262144, bk, nullptr, kf, 512, 512, 512, 512, 0, 0);
  mm_f16<1, true, false><<<gproj, 256, 0, stream>>>(h, wf + 524288, bv, nullptr, vf, 512, 512, 512, 512, 0, 0);

  for (int b = 0; b < BATCH; b++) {
    transpose_f16<<<dim3(64, 8, 2), 256, 0, stream>>>(qf + (long)b * CNT, kf + (long)b * CNT, tr);
    // attn[n,m] = sum_c qT[n][c]*kT[m][c]
    mm_f16<1, false, true><<<dim3(32, 32), 256, 0, stream>>>(tr, tr + 2097152, nullptr, nullptr, attn,
                                                             512, 512, 4096, 512, 0, 0);
    softmax_f16ip<<<dim3(4096), 256, 0, stream>>>(attn);
    // pv partial[n,c] = sum_{m in quarter} P[n,m]*V[c,m]
    mm_f16<1, false, false><<<dim3(32, 4, 4), 256, 0, stream>>>(attn, vf + (long)b * CNT, nullptr, nullptr, pvp,
                                                                4096, 4096, 512, 1024, 1024, 2097152);
    add4_f16<<<dim3(2048), 256, 0, stream>>>(pvp, ot + (long)b * CNT);
  }
  mm_f16<0, true, false><<<gproj, 256, 0, stream>>>(ot, wf + 786432, bo, x, (void*)out, 512, 512, 512, 512, 0, 0);
}

// Round 7
// 614.518 us; speedup vs baseline: 1.3754x; 1.3754x over previous
//
#include <hip/hip_runtime.h>
#include <hip/hip_fp16.h>
#include <math.h>

// Shapes (fixed): B=4, C=512, H=W=64 -> HW=4096
constexpr int BATCH = 4;
constexpr int HWDIM = 4096;
constexpr long CNT  = 2097152;               // 4096*512 elems per batch
constexpr int GSIZE = 65536;
constexpr float GN_EPS = 1e-5f;

typedef __attribute__((ext_vector_type(8))) _Float16 f16x8;
typedef __attribute__((ext_vector_type(4))) float f32x4;

__device__ __forceinline__ unsigned pkf16(float a, float b) {
  __half ha = __float2half(a), hb = __float2half(b);   // RTN
  return (unsigned)__half_as_ushort(ha) | ((unsigned)__half_as_ushort(hb) << 16);
}
__device__ __forceinline__ float2 up2(unsigned u) {
  __half2 h = *(__half2*)&u;
  return __half22float2(h);
}
// async global->LDS, 16B per lane; LDS dest = base + lane*16
__device__ __forceinline__ void gl_lds16(const void* g, void* l) {
  __builtin_amdgcn_global_load_lds((const __attribute__((address_space(1))) unsigned*)g,
                                   (__attribute__((address_space(3))) unsigned*)l, 16, 0, 0);
}

// ---------------- GroupNorm ----------------
__global__ void gn_stats_kernel(const float* __restrict__ x,
                                float* __restrict__ mu, float* __restrict__ rs) {
  const int grp = blockIdx.x;
  const float4* p = (const float4*)(x + (long)grp * GSIZE);
  float s = 0.f, q = 0.f;
  for (int i = threadIdx.x; i < GSIZE / 4; i += 256) {
    float4 v = p[i];
    s += (v.x + v.y) + (v.z + v.w);
    q += (v.x * v.x + v.y * v.y) + (v.z * v.z + v.w * v.w);
  }
  #pragma unroll
  for (int o = 32; o > 0; o >>= 1) { s += __shfl_xor(s, o, 64); q += __shfl_xor(q, o, 64); }
  __shared__ float ls[4], lq[4];
  if ((threadIdx.x & 63) == 0) { ls[threadIdx.x >> 6] = s; lq[threadIdx.x >> 6] = q; }
  __syncthreads();
  if (threadIdx.x == 0) {
    float S = (ls[0] + ls[1]) + (ls[2] + ls[3]);
    float Q = (lq[0] + lq[1]) + (lq[2] + lq[3]);
    float m = S * (1.f / GSIZE);
    float var = Q * (1.f / GSIZE) - m * m;
    mu[grp] = m; rs[grp] = rsqrtf(var + GN_EPS);
  }
}

__global__ void gn_norm_f16(const float* __restrict__ x,
                            const float* __restrict__ mu, const float* __restrict__ rs,
                            const float* __restrict__ gw, const float* __restrict__ gb,
                            unsigned short* __restrict__ h) {
  long i = ((long)blockIdx.x * 256 + threadIdx.x) * 4;
  int c   = (int)((i >> 12) & 511);
  int grp = (int)(i >> 16);
  float m = mu[grp], r = rs[grp];
  float w = gw[c] * r;
  float bia = gb[c] - m * w;
  float4 v = *(const float4*)(x + i);
  *(uint2*)(h + i) = (uint2){ pkf16(v.x * w + bia, v.y * w + bia),
                              pkf16(v.z * w + bia, v.w * w + bia) };
}

// ---------------- weights -> fp16 ----------------
__global__ void wcvt(const float* __restrict__ w0, const float* __restrict__ w1,
                     const float* __restrict__ w2, const float* __restrict__ w3,
                     unsigned short* __restrict__ o) {
  const float* src = blockIdx.y == 0 ? w0 : blockIdx.y == 1 ? w1 : blockIdx.y == 2 ? w2 : w3;
  long e = ((long)blockIdx.x * 256 + threadIdx.x) * 4;
  float4 v = *(const float4*)(src + e);
  *(uint2*)(o + (long)blockIdx.y * 262144 + e) = (uint2){ pkf16(v.x, v.y), pkf16(v.z, v.w) };
}

// ---------------- Projection GEMM (R5-proven), fp16 MFMA, full-DMA staging ----------------
template<int OMODE>
__launch_bounds__(256)
__global__ void proj_f16(const unsigned short* __restrict__ A, const unsigned short* __restrict__ W,
                         const float* __restrict__ bias, const float* __restrict__ res,
                         void* __restrict__ outv) {
  __shared__ __align__(16) unsigned short LB[17408];
  unsigned short* As = LB;
  unsigned short* Bs = LB + 8192;
  const int m0 = blockIdx.x * 128, n0 = blockIdx.y * 128;
  const int t = threadIdx.x, lane = t & 63, w = t >> 6, wm = w & 1, wn = w >> 1;

  f32x4 acc[4][4];
  #pragma unroll
  for (int i = 0; i < 4; i++)
    #pragma unroll
    for (int j = 0; j < 4; j++) acc[i][j] = (f32x4){0.f, 0.f, 0.f, 0.f};

  for (int k0 = 0; k0 < 512; k0 += 64) {
    __syncthreads();
    #pragma unroll
    for (int fbi = 0; fbi < 4; fbi++) {
      int fb = w * 4 + fbi;
      int row = (fb >> 1) * 16 + (lane & 15);
      int g   = (fb & 1) * 4 + (lane >> 4);
      gl_lds16(A + (long)(m0 + row) * 512 + k0 + g * 8, &As[(fb * 64) << 3]);
      gl_lds16(W + (long)(n0 + row) * 512 + k0 + g * 8, &Bs[(fb * 64) << 3]);
    }
    __syncthreads();
    #pragma unroll
    for (int kk = 0; kk < 2; kk++) {
      f16x8 a[4], b[4];
      #pragma unroll
      for (int i = 0; i < 4; i++)
        a[i] = *(const f16x8*)&As[(((wm * 4 + i) * 2 + kk) * 64 + lane) << 3];
      #pragma unroll
      for (int j = 0; j < 4; j++)
        b[j] = *(const f16x8*)&Bs[(((wn * 4 + j) * 2 + kk) * 64 + lane) << 3];
      #pragma unroll
      for (int i = 0; i < 4; i++)
        #pragma unroll
        for (int j = 0; j < 4; j++)
          acc[i][j] = __builtin_amdgcn_mfma_f32_16x16x32_f16(a[i], b[j], acc[i][j], 0, 0, 0);
    }
  }

  const int lm = lane & 15, quad = lane >> 4;
  if (OMODE == 1) {
    __syncthreads();
    #pragma unroll
    for (int i = 0; i < 4; i++)
      #pragma unroll
      for (int j = 0; j < 4; j++) {
        int rr = wm * 64 + i * 16 + quad * 4;
        int cc = wn * 64 + j * 16 + lm;
        float bb = bias[n0 + cc];
        #pragma unroll
        for (int r = 0; r < 4; r++)
          LB[(rr + r) * 136 + cc] = __half_as_ushort(__float2half(acc[i][j][r] + bb));
      }
    __syncthreads();
    #pragma unroll
    for (int k = 0; k < 8; k++) {
      int ro = k * 16 + (t >> 4), col = (t & 15) * 8;
      uint4 vv = *(const uint4*)&LB[ro * 136 + col];
      *(uint4*)((unsigned short*)outv + (long)(m0 + ro) * 512 + n0 + col) = vv;
    }
  } else {
    #pragma unroll
    for (int i = 0; i < 4; i++)
      #pragma unroll
      for (int j = 0; j < 4; j++) {
        int nn = m0 + wm * 64 + i * 16 + quad * 4;
        int cc = n0 + wn * 64 + j * 16 + lm;
        float bb = bias[cc];
        #pragma unroll
        for (int r = 0; r < 4; r++) {
          long idx = (long)(nn + r) * 512 + cc;
          ((float*)outv)[idx] = acc[i][j][r] + bb + res[idx];
        }
      }
  }
}

// ---------------- Transpose all batches: (512,4096)-view -> [4096][512] ----------------
// grid (64, 8, 8): z = batch*2 + (0=q, 1=k). Out: tr4 + batch*4M + sel*2M.
__global__ void transpose_all(const unsigned short* __restrict__ qf,
                              const unsigned short* __restrict__ kf,
                              unsigned short* __restrict__ tr4) {
  __shared__ __align__(16) unsigned short ld[64 * 72];
  const int z = blockIdx.z, b = z >> 1;
  const unsigned short* in = ((z & 1) ? kf : qf) + (long)b * CNT;
  unsigned short* o = tr4 + (long)b * 4194304 + ((z & 1) ? 2097152 : 0);
  const int n0 = blockIdx.x * 64, c0 = blockIdx.y * 64;
  const int t = threadIdx.x;
  unsigned* ld32 = (unsigned*)ld;
  {
    const int p = t >> 3, cg = t & 7;
    uint4 r0 = *(const uint4*)(in + (long)(c0 + 2 * p) * 4096 + n0 + 8 * cg);
    uint4 r1 = *(const uint4*)(in + (long)(c0 + 2 * p + 1) * 4096 + n0 + 8 * cg);
    unsigned aw[4] = { r0.x, r0.y, r0.z, r0.w };
    unsigned bw[4] = { r1.x, r1.y, r1.z, r1.w };
    #pragma unroll
    for (int i = 0; i < 4; i++) {
      ld32[(8 * cg + 2 * i) * 36 + p]     = (aw[i] & 0xFFFFu) | (bw[i] << 16);
      ld32[(8 * cg + 2 * i + 1) * 36 + p] = (aw[i] >> 16) | (bw[i] & 0xFFFF0000u);
    }
  }
  __syncthreads();
  {
    const int n = t >> 2, cg2 = t & 3;
    uint4 o0 = *(const uint4*)(ld + n * 72 + 16 * cg2);
    uint4 o1 = *(const uint4*)(ld + n * 72 + 16 * cg2 + 8);
    *(uint4*)(o + (long)(n0 + n) * 512 + c0 + 16 * cg2)     = o0;
    *(uint4*)(o + (long)(n0 + n) * 512 + c0 + 16 * cg2 + 8) = o1;
  }
}

// ---------------- QK^T fp16, full DMA, fp16 S out, XCD-aware swizzle ----------------
// attn16[n,m] = sum_c qT[n][c]*kT[m][c]; 128x128 tiles, K=512, grid (32,32).
// Swizzle: lin&7 tracks the XCD round-robin -> each XCD owns a 4-wide bx band
// (A-band 512 KB stays L2-resident; B tiles reused 4x within the XCD).
__launch_bounds__(256)
__global__ void qk_f16(const unsigned short* __restrict__ tr, unsigned short* __restrict__ attn) {
  __shared__ __align__(16) unsigned short LB[17408];
  unsigned short* As = LB;
  unsigned short* Bs = LB + 8192;
  const unsigned short* qT = tr;
  const unsigned short* kT = tr + 2097152;
  const int lin = blockIdx.y * 32 + blockIdx.x;
  const int x7 = lin & 7, sl = lin >> 3;
  const int n0 = (x7 * 4 + (sl & 3)) * 128;     // bx band per XCD
  const int m0 = (sl >> 2) * 128;               // by sweep
  const int t = threadIdx.x, lane = t & 63, w = t >> 6, wm = w & 1, wn = w >> 1;

  f32x4 acc[4][4];
  #pragma unroll
  for (int i = 0; i < 4; i++)
    #pragma unroll
    for (int j = 0; j < 4; j++) acc[i][j] = (f32x4){0.f, 0.f, 0.f, 0.f};

  for (int k0 = 0; k0 < 512; k0 += 64) {
    __syncthreads();
    #pragma unroll
    for (int fbi = 0; fbi < 4; fbi++) {
      int fb = w * 4 + fbi;
      int row = (fb >> 1) * 16 + (lane & 15);
      int g   = (fb & 1) * 4 + (lane >> 4);
      gl_lds16(qT + (long)(n0 + row) * 512 + k0 + g * 8, &As[(fb * 64) << 3]);
      gl_lds16(kT + (long)(m0 + row) * 512 + k0 + g * 8, &Bs[(fb * 64) << 3]);
    }
    __syncthreads();
    #pragma unroll
    for (int kk = 0; kk < 2; kk++) {
      f16x8 a[4], b[4];
      #pragma unroll
      for (int i = 0; i < 4; i++)
        a[i] = *(const f16x8*)&As[(((wm * 4 + i) * 2 + kk) * 64 + lane) << 3];
      #pragma unroll
      for (int j = 0; j < 4; j++)
        b[j] = *(const f16x8*)&Bs[(((wn * 4 + j) * 2 + kk) * 64 + lane) << 3];
      #pragma unroll
      for (int i = 0; i < 4; i++)
        #pragma unroll
        for (int j = 0; j < 4; j++)
          acc[i][j] = __builtin_amdgcn_mfma_f32_16x16x32_f16(a[i], b[j], acc[i][j], 0, 0, 0);
    }
  }

  const int lm = lane & 15, quad = lane >> 4;
  __syncthreads();
  #pragma unroll
  for (int i = 0; i < 4; i++)
    #pragma unroll
    for (int j = 0; j < 4; j++) {
      int rr = wm * 64 + i * 16 + quad * 4;
      int cc = wn * 64 + j * 16 + lm;
      #pragma unroll
      for (int r = 0; r < 4; r++)
        LB[(rr + r) * 136 + cc] = __half_as_ushort(__float2half(acc[i][j][r]));
    }
  __syncthreads();
  #pragma unroll
  for (int k = 0; k < 8; k++) {
    int ro = k * 16 + (t >> 4), col = (t & 15) * 8;
    uint4 vv = *(const uint4*)&LB[ro * 136 + col];
    *(uint4*)(attn + (long)(n0 + ro) * 4096 + m0 + col) = vv;
  }
}

// ---------------- Row softmax: fp16 in/out, in place ----------------
__global__ void softmax_f16ip(unsigned short* __restrict__ attn) {
  unsigned short* p = attn + (long)blockIdx.x * HWDIM;
  const int t = threadIdx.x;
  uint4 u0 = *(const uint4*)(p + t * 16);
  uint4 u1 = *(const uint4*)(p + t * 16 + 8);
  float v[16];
  {
    unsigned uu[8] = { u0.x, u0.y, u0.z, u0.w, u1.x, u1.y, u1.z, u1.w };
    #pragma unroll
    for (int i = 0; i < 8; i++) { float2 f = up2(uu[i]); v[2*i] = f.x; v[2*i+1] = f.y; }
  }
  float mx = -1e30f;
  #pragma unroll
  for (int i = 0; i < 16; i++) mx = fmaxf(mx, v[i]);
  #pragma unroll
  for (int o = 32; o > 0; o >>= 1) mx = fmaxf(mx, __shfl_xor(mx, o, 64));
  __shared__ float rmax[4], rsum[4];
  if ((t & 63) == 0) rmax[t >> 6] = mx;
  __syncthreads();
  mx = fmaxf(fmaxf(rmax[0], rmax[1]), fmaxf(rmax[2], rmax[3]));
  float s = 0.f;
  #pragma unroll
  for (int i = 0; i < 16; i++) { v[i] = __expf(v[i] - mx); s += v[i]; }
  #pragma unroll
  for (int o = 32; o > 0; o >>= 1) s += __shfl_xor(s, o, 64);
  if ((t & 63) == 0) rsum[t >> 6] = s;
  __syncthreads();
  s = (rsum[0] + rsum[1]) + (rsum[2] + rsum[3]);
  float inv = 1.f / s;
  uint4 w0, w1;
  w0.x = pkf16(v[0]*inv,  v[1]*inv);  w0.y = pkf16(v[2]*inv,  v[3]*inv);
  w0.z = pkf16(v[4]*inv,  v[5]*inv);  w0.w = pkf16(v[6]*inv,  v[7]*inv);
  w1.x = pkf16(v[8]*inv,  v[9]*inv);  w1.y = pkf16(v[10]*inv, v[11]*inv);
  w1.z = pkf16(v[12]*inv, v[13]*inv); w1.w = pkf16(v[14]*inv, v[15]*inv);
  *(uint4*)(p + t * 16)     = w0;
  *(uint4*)(p + t * 16 + 8) = w1;
}

// ---------------- PV: fp16 P x fp16 V, full DMA, split-K 8 ----------------
// grid (32, 4, 8); z = K-chunk of 512 -> partial plane z (fp16).
__launch_bounds__(256)
__global__ void pv_f16(const unsigned short* __restrict__ P, const unsigned short* __restrict__ V,
                       unsigned short* __restrict__ pvp) {
  __shared__ __align__(16) unsigned short LB[17408];
  unsigned short* As = LB;
  unsigned short* Bs = LB + 8192;
  const int n0 = blockIdx.x * 128, c0 = blockIdx.y * 128;
  const long kbase = (long)blockIdx.z * 512;
  unsigned short* __restrict__ Pout = pvp + (long)blockIdx.z * 2097152;
  const int t = threadIdx.x, lane = t & 63, w = t >> 6, wm = w & 1, wn = w >> 1;

  f32x4 acc[4][4];
  #pragma unroll
  for (int i = 0; i < 4; i++)
    #pragma unroll
    for (int j = 0; j < 4; j++) acc[i][j] = (f32x4){0.f, 0.f, 0.f, 0.f};

  for (int k0 = 0; k0 < 512; k0 += 64) {
    __syncthreads();
    #pragma unroll
    for (int fbi = 0; fbi < 4; fbi++) {
      int fb = w * 4 + fbi;
      int row = (fb >> 1) * 16 + (lane & 15);
      int g   = (fb & 1) * 4 + (lane >> 4);
      gl_lds16(P + (long)(n0 + row) * 4096 + kbase + k0 + g * 8, &As[(fb * 64) << 3]);
      gl_lds16(V + (long)(c0 + row) * 4096 + kbase + k0 + g * 8, &Bs[(fb * 64) << 3]);
    }
    __syncthreads();
    #pragma unroll
    for (int kk = 0; kk < 2; kk++) {
      f16x8 a[4], b[4];
      #pragma unroll
      for (int i = 0; i < 4; i++)
        a[i] = *(const f16x8*)&As[(((wm * 4 + i) * 2 + kk) * 64 + lane) << 3];
      #pragma unroll
      for (int j = 0; j < 4; j++)
        b[j] = *(const f16x8*)&Bs[(((wn * 4 + j) * 2 + kk) * 64 + lane) << 3];
      #pragma unroll
      for (int i = 0; i < 4; i++)
        #pragma unroll
        for (int j = 0; j < 4; j++)
          acc[i][j] = __builtin_amdgcn_mfma_f32_16x16x32_f16(a[i], b[j], acc[i][j], 0, 0, 0);
    }
  }

  const int lm = lane & 15, quad = lane >> 4;
  __syncthreads();
  #pragma unroll
  for (int i = 0; i < 4; i++)
    #pragma unroll
    for (int j = 0; j < 4; j++) {
      int rr = wm * 64 + i * 16 + quad * 4;
      int cc = wn * 64 + j * 16 + lm;
      #pragma unroll
      for (int r = 0; r < 4; r++)
        LB[(rr + r) * 136 + cc] = __half_as_ushort(__float2half(acc[i][j][r]));
    }
  __syncthreads();
  #pragma unroll
  for (int k = 0; k < 8; k++) {
    int ro = k * 16 + (t >> 4), col = (t & 15) * 8;
    uint4 vv = *(const uint4*)&LB[ro * 136 + col];
    *(uint4*)(Pout + (long)(n0 + ro) * 512 + c0 + col) = vv;
  }
}

// ---------------- sum 8 fp16 partials -> fp16 ot ----------------
__global__ void add8_f16(const unsigned short* __restrict__ p, unsigned short* __restrict__ o) {
  long e = ((long)blockIdx.x * 256 + threadIdx.x) * 4;
  float sx = 0.f, sy = 0.f, sz = 0.f, sw = 0.f;
  #pragma unroll
  for (int z = 0; z < 8; z++) {
    uint2 u = *(const uint2*)(p + (long)z * 2097152 + e);
    float2 f0 = up2(u.x), f1 = up2(u.y);
    sx += f0.x; sy += f0.y; sz += f1.x; sw += f1.y;
  }
  *(uint2*)(o + e) = (uint2){ pkf16(sx, sy), pkf16(sz, sw) };
}

// ---------------- launch ----------------
extern "C" void kernel_launch(void* const* d_in, const int* in_sizes, int n_in,
                              void* d_out, int out_size, void* d_ws, size_t ws_size,
                              hipStream_t stream) {
  (void)in_sizes; (void)n_in; (void)out_size; (void)ws_size;
  const float* x  = (const float*)d_in[0];
  const float* gw = (const float*)d_in[1];
  const float* gb = (const float*)d_in[2];
  const float* wq = (const float*)d_in[3];
  const float* bq = (const float*)d_in[4];
  const float* wk = (const float*)d_in[5];
  const float* bk = (const float*)d_in[6];
  const float* wv = (const float*)d_in[7];
  const float* bv = (const float*)d_in[8];
  const float* wo = (const float*)d_in[9];
  const float* bo = (const float*)d_in[10];
  float* out = (float*)d_out;

  // Workspace (~136 MB):
  //  [attn 32MB | h 16MB aliases start][qf 16][kf 16][vf 16][tr4 32][ot 16][wf 2][mu/rs]
  //  pvp (32MB, 8 fp16 planes) aliases qf+kf (both dead after transpose_all).
  unsigned short* attn = (unsigned short*)d_ws;
  unsigned short* h    = attn;
  unsigned short* qf   = attn + 16777216;
  unsigned short* kf   = qf + 8388608;
  unsigned short* pvp  = qf;                   // 16777216 shorts = qf+kf regions
  unsigned short* vf   = kf + 8388608;
  unsigned short* tr4  = vf + 8388608;
  unsigned short* ot   = tr4 + 16777216;
  unsigned short* wf   = ot + 8388608;
  float* mu = (float*)(wf + 1048576);
  float* rs = mu + 128;

  gn_stats_kernel<<<dim3(128), dim3(256), 0, stream>>>(x, mu, rs);
  gn_norm_f16<<<dim3(8192), dim3(256), 0, stream>>>(x, mu, rs, gw, gb, h);
  wcvt<<<dim3(256, 4), dim3(256), 0, stream>>>(wq, wk, wv, wo, wf);

  dim3 gproj(128, 4);
  proj_f16<1><<<gproj, 256, 0, stream>>>(h, wf,          bq, nullptr, qf);
  proj_f16<1><<<gproj, 256, 0, stream>>>(h, wf + 262144, bk, nullptr, kf);
  proj_f16<1><<<gproj, 256, 0, stream>>>(h, wf + 524288, bv, nullptr, vf);

  transpose_all<<<dim3(64, 8, 8), 256, 0, stream>>>(qf, kf, tr4);

  for (int b = 0; b < BATCH; b++) {
    qk_f16<<<dim3(32, 32), 256, 0, stream>>>(tr4 + (long)b * 4194304, attn);
    softmax_f16ip<<<dim3(4096), 256, 0, stream>>>(attn);
    pv_f16<<<dim3(32, 4, 8), 256, 0, stream>>>(attn, vf + (long)b * CNT, pvp);
    add8_f16<<<dim3(2048), 256, 0, stream>>>(pvp, ot + (long)b * CNT);
  }
  proj_f16<0><<<gproj, 256, 0, stream>>>(ot, wf + 786432, bo, x, (void*)out);
}